// Round 12
// baseline (298.390 us; speedup 1.0000x reference)
//
#include <hip/hip_runtime.h>

#define NN    50000      // nodes
#define NE    800000     // edges (without self loops)
#define NET   850000     // NE + NN (with self loops)
#define NBUCK ((NN + 255) / 256)   // 196 dst-buckets of 256 nodes
#define MAXB  8192       // padded slots per bucket (avg 4352, sigma 66)
#define GB    ((NN + 63) / 64)     // 782 gemm-role blocks
#define BINB  ((NET + 255) / 256)  // 3321 bin-role blocks

typedef __fp16 half2_t __attribute__((ext_vector_type(2)));
typedef _Float16 half8 __attribute__((ext_vector_type(8)));
typedef float floatx4 __attribute__((ext_vector_type(4)));

__device__ __forceinline__ float lrelu(float v) { return fmaxf(v, 0.2f * v); }
__device__ __forceinline__ unsigned pk16(float a, float b) {
    half2_t h = __builtin_amdgcn_cvt_pkrtz(a, b);
    return __builtin_bit_cast(unsigned, h);
}
__device__ __forceinline__ float2 unpk16(unsigned u) {
    half2_t h = __builtin_bit_cast(half2_t, u);
    return make_float2((float)h.x, (float)h.y);
}

// ---------------------------------------------------------------------------
// Fused dispatch 1: blocks [0,GB) = gemm1+alpha1 (self-staging W1->w1t via a
// benign redundant-write race); blocks [GB, GB+BINB) = bin (+W2 prep in the
// first 32 bin blocks). gemm1 and bin are independent -> they overlap.
// ---------------------------------------------------------------------------
__global__ __launch_bounds__(256) void gemm1_bin_kernel(
    const float* __restrict__ x, const float* __restrict__ W1,
    const float* __restrict__ W2, const int* __restrict__ ei,
    const float* __restrict__ att_s, const float* __restrict__ att_d,
    _Float16* __restrict__ w1t, _Float16* __restrict__ w2t,
    _Float16* __restrict__ h1h, float* __restrict__ as, float* __restrict__ ad,
    int* __restrict__ bcnt, unsigned* __restrict__ pairs)
{
    const int t = threadIdx.x;

    if (blockIdx.x >= GB) {
        // ---------------- bin role ----------------
        const int bb = blockIdx.x - GB;
        if (bb < 32) {   // W2 prep: 32*256 = 8192 elements exact
            const int idx = bb * 256 + t;
            const int k = idx >> 6, n = idx & 63;
            w2t[n * 128 + k] = (_Float16)W2[idx];
        }
        __shared__ int hist[NBUCK], base[NBUCK], cur[NBUCK];
        if (t < NBUCK) { hist[t] = 0; cur[t] = 0; }
        __syncthreads();
        const int e = bb * 256 + t;
        int s = 0, d = 0, bk = 0;
        const bool ok = e < NET;
        if (ok) {
            if (e < NE) { s = ei[e]; d = ei[NE + e]; } else { s = d = e - NE; }
            bk = d >> 8;
            atomicAdd(&hist[bk], 1);
        }
        __syncthreads();
        if (t < NBUCK && hist[t]) base[t] = atomicAdd(&bcnt[t], hist[t]);
        __syncthreads();
        if (ok) {
            const int r = atomicAdd(&cur[bk], 1);
            pairs[(size_t)bk * MAXB + base[bk] + r] =
                (unsigned)s | ((unsigned)(d & 255) << 16);
        }
        return;
    }

    // ---------------- gemm1 role (verified R8-R11 body) ----------------
    // self-stage W1 -> w1t (fp16, [n][k]): every gemm block writes the same
    // values (benign race); __syncthreads drains vmcnt before reads.
    for (int idx = t; idx < 16384; idx += 256)
        w1t[(idx & 127) * 128 + (idx >> 7)] = (_Float16)W1[idx];

    __shared__ _Float16 hs[64 * 128];   // 16 KB
    const int lane = t & 63;
    const int m    = lane & 15;
    const int q    = lane >> 4;
    const int wv   = t >> 6;
    const int gr0  = blockIdx.x * 64;
    const int rbase = gr0 + wv * 16;

    const int rme = rbase + m;
    const int rc  = rme < NN ? rme : NN - 1;
    const float* ap = x + (size_t)rc * 128 + q * 8;

    floatx4 acc[8];
#pragma unroll
    for (int nt = 0; nt < 8; nt++) acc[nt] = (floatx4){0.f, 0.f, 0.f, 0.f};

    __syncthreads();   // w1t writes drained (vmcnt) + all threads done staging

#pragma unroll
    for (int ks = 0; ks < 4; ks++) {
        const float4 f0 = *(const float4*)(ap + ks * 32);
        const float4 f1 = *(const float4*)(ap + ks * 32 + 4);
        const uint4 au = make_uint4(pk16(f0.x, f0.y), pk16(f0.z, f0.w),
                                    pk16(f1.x, f1.y), pk16(f1.z, f1.w));
        const half8 a = __builtin_bit_cast(half8, au);
#pragma unroll
        for (int nt = 0; nt < 8; nt++) {
            const half8 b = *(const half8*)(w1t + (nt * 16 + m) * 128 + ks * 32 + q * 8);
            acc[nt] = __builtin_amdgcn_mfma_f32_16x16x32_f16(a, b, acc[nt], 0, 0, 0);
        }
    }

    const int lrow0 = wv * 16 + q * 4;
#pragma unroll
    for (int nt = 0; nt < 8; nt++)
#pragma unroll
        for (int r = 0; r < 4; r++)
            hs[(lrow0 + r) * 128 + nt * 16 + m] = (_Float16)acc[nt][r];
    __syncthreads();

#pragma unroll
    for (int i = t; i < 1024; i += 256) {
        const int row = i >> 4;
        if (gr0 + row < NN)
            ((half8*)h1h)[(size_t)(gr0 + row) * 16 + (i & 15)] = ((const half8*)hs)[i];
    }

    const int arow = t >> 2, hd = t & 3;
    const int grow = gr0 + arow;
    float ps = 0.f, pd = 0.f;
    const half8*  hp8 = (const half8*)(hs + arow * 128 + hd * 32);
    const float4* s4  = (const float4*)(att_s + hd * 32);
    const float4* d4  = (const float4*)(att_d + hd * 32);
#pragma unroll
    for (int cc = 0; cc < 4; cc++) {
        const half8 hv = hp8[cc];
        const float4 a = s4[cc * 2], b = s4[cc * 2 + 1];
        const float4 c = d4[cc * 2], e = d4[cc * 2 + 1];
        ps += (float)hv[0]*a.x + (float)hv[1]*a.y + (float)hv[2]*a.z + (float)hv[3]*a.w
            + (float)hv[4]*b.x + (float)hv[5]*b.y + (float)hv[6]*b.z + (float)hv[7]*b.w;
        pd += (float)hv[0]*c.x + (float)hv[1]*c.y + (float)hv[2]*c.z + (float)hv[3]*c.w
            + (float)hv[4]*e.x + (float)hv[5]*e.y + (float)hv[6]*e.z + (float)hv[7]*e.w;
    }
    if (grow < NN) {
        as[grow * 4 + hd] = ps;
        ad[grow * 4 + hd] = pd;
    }
}

// ---------------------------------------------------------------------------
// MFMA GEMM2 + alpha2 (verified R8-R11)
// ---------------------------------------------------------------------------
__global__ __launch_bounds__(256) void gemm2_mfma_kernel(
    const _Float16* __restrict__ ah, const _Float16* __restrict__ w2t,
    const float* __restrict__ att_s, const float* __restrict__ att_d,
    _Float16* __restrict__ h2h, float* __restrict__ as, float* __restrict__ ad)
{
    __shared__ _Float16 hs[64 * 64];    // 8 KB
    const int t    = threadIdx.x;
    const int lane = t & 63;
    const int m    = lane & 15;
    const int q    = lane >> 4;
    const int wv   = t >> 6;
    const int gr0  = blockIdx.x * 64;
    const int rbase = gr0 + wv * 16;

    const int rme = rbase + m;
    const int rc  = rme < NN ? rme : NN - 1;
    const _Float16* ap = ah + (size_t)rc * 128 + q * 8;

    floatx4 acc[4];
#pragma unroll
    for (int nt = 0; nt < 4; nt++) acc[nt] = (floatx4){0.f, 0.f, 0.f, 0.f};

#pragma unroll
    for (int ks = 0; ks < 4; ks++) {
        const half8 a = *(const half8*)(ap + ks * 32);
#pragma unroll
        for (int nt = 0; nt < 4; nt++) {
            const half8 b = *(const half8*)(w2t + (nt * 16 + m) * 128 + ks * 32 + q * 8);
            acc[nt] = __builtin_amdgcn_mfma_f32_16x16x32_f16(a, b, acc[nt], 0, 0, 0);
        }
    }

    const int lrow0 = wv * 16 + q * 4;
#pragma unroll
    for (int nt = 0; nt < 4; nt++)
#pragma unroll
        for (int r = 0; r < 4; r++)
            hs[(lrow0 + r) * 64 + nt * 16 + m] = (_Float16)acc[nt][r];
    __syncthreads();

#pragma unroll
    for (int i = t; i < 512; i += 256) {
        const int row = i >> 3;
        if (gr0 + row < NN)
            ((half8*)h2h)[(size_t)(gr0 + row) * 8 + (i & 7)] = ((const half8*)hs)[i];
    }

    const int arow = t >> 2, sg = t & 3;
    const int grow = gr0 + arow;
    float ps = 0.f, pd = 0.f;
    const half8*  hp8 = (const half8*)(hs + arow * 64 + sg * 16);
    const float4* s4  = (const float4*)(att_s + sg * 16);
    const float4* d4  = (const float4*)(att_d + sg * 16);
#pragma unroll
    for (int cc = 0; cc < 2; cc++) {
        const half8 hv = hp8[cc];
        const float4 a = s4[cc * 2], b = s4[cc * 2 + 1];
        const float4 c = d4[cc * 2], e = d4[cc * 2 + 1];
        ps += (float)hv[0]*a.x + (float)hv[1]*a.y + (float)hv[2]*a.z + (float)hv[3]*a.w
            + (float)hv[4]*b.x + (float)hv[5]*b.y + (float)hv[6]*b.z + (float)hv[7]*b.w;
        pd += (float)hv[0]*c.x + (float)hv[1]*c.y + (float)hv[2]*c.z + (float)hv[3]*c.w
            + (float)hv[4]*e.x + (float)hv[5]*e.y + (float)hv[6]*e.z + (float)hv[7]*e.w;
    }
    ps += __shfl_down(ps, 2);  pd += __shfl_down(pd, 2);
    ps += __shfl_down(ps, 1);  pd += __shfl_down(pd, 1);
    if (sg == 0 && grow < NN) { as[grow] = ps; ad[grow] = pd; }
}

// ---------------------------------------------------------------------------
// bsort (verified R11): 1024 threads, packed pairs, per-bucket counting sort.
// ---------------------------------------------------------------------------
__global__ __launch_bounds__(1024) void bsort_kernel(
    const int* __restrict__ bcnt, const unsigned* __restrict__ pairs,
    int* __restrict__ row_beg, int* __restrict__ row_end,
    int* __restrict__ col)
{
    __shared__ int hist[256], cur[256], sh[256];
    __shared__ int outl[MAXB];
    const int b = blockIdx.x, t = threadIdx.x;
    const int m = bcnt[b];
    const int gbase = b * MAXB;
    if (t < 256) hist[t] = 0;
    __syncthreads();
    for (int i = t; i < m; i += 1024)
        atomicAdd(&hist[pairs[gbase + i] >> 16], 1);
    __syncthreads();
    if (t < 256) sh[t] = hist[t];
    __syncthreads();
#pragma unroll
    for (int off = 1; off < 256; off <<= 1) {
        int u = (t < 256 && t >= off) ? sh[t - off] : 0;
        __syncthreads();
        if (t < 256) sh[t] += u;
        __syncthreads();
    }
    if (t < 256) {
        const int ex = sh[t] - hist[t];
        cur[t] = ex;
        const int node = (b << 8) + t;
        if (node < NN) {
            row_beg[node] = gbase + ex;
            row_end[node] = gbase + ex + hist[t];
        }
    }
    __syncthreads();
    for (int i = t; i < m; i += 1024) {
        const unsigned p = pairs[gbase + i];
        const int r = atomicAdd(&cur[p >> 16], 1);
        outl[r] = (int)(p & 0xFFFFu);
    }
    __syncthreads();
    for (int i = t; i < m; i += 1024) col[gbase + i] = outl[i];
}

// ---------------------------------------------------------------------------
// Fused layer-1 tail (verified R10/R11): LDS-staged lane-parallel weights.
// ---------------------------------------------------------------------------
__global__ __launch_bounds__(256) void agg1_fused_kernel(
    const int* __restrict__ row_beg, const int* __restrict__ row_end,
    const int* __restrict__ col, const unsigned* __restrict__ hh,
    const float* __restrict__ as1, const float* __restrict__ ad1,
    const float* __restrict__ b1, unsigned* __restrict__ acth)
{
    __shared__ float wbuf[4][64 * 4];   // [wave][edge*4+head], 4 KB
    const int wv   = threadIdx.x >> 6;
    const int d    = __builtin_amdgcn_readfirstlane((blockIdx.x * 256 + threadIdx.x) >> 6);
    const int lane = threadIdx.x & 63;
    const int head = lane >> 4;
    const int beg = row_beg[d], end = row_end[d];       // s_loads (d uniform)
    const float4 ad4 = ((const float4*)ad1)[d];
    float* wb = wbuf[wv];

    float acc0 = 0.f, acc1 = 0.f, den = 0.f;

    for (int jb = beg; jb < end; jb += 64) {
        const int cnt = min(64, end - jb);
        {
            const int sl = col[jb + min(lane, cnt - 1)];
            const float4 a = ((const float4*)as1)[sl];
            float4 w4;
            w4.x = __expf(lrelu(a.x + ad4.x));
            w4.y = __expf(lrelu(a.y + ad4.y));
            w4.z = __expf(lrelu(a.z + ad4.z));
            w4.w = __expf(lrelu(a.w + ad4.w));
            ((float4*)wb)[lane] = w4;
        }
        __asm__ volatile("s_waitcnt lgkmcnt(0)" ::: "memory");

        int k = 0;
        for (; k + 16 <= cnt; k += 16) {
            float    w[16];
            unsigned g[16];
#pragma unroll
            for (int u = 0; u < 16; u++) {
                const int s = col[jb + k + u];        // s_load (uniform)
                w[u] = wb[(k + u) * 4 + head];        // ds_read broadcast
                g[u] = hh[s * 64 + lane];             // saddr + voffset
            }
#pragma unroll
            for (int u = 0; u < 16; u++) {
                const float2 g2 = unpk16(g[u]);
                den  += w[u];
                acc0 += w[u] * g2.x;
                acc1 += w[u] * g2.y;
            }
        }
        for (; k + 4 <= cnt; k += 4) {
            float    w[4];
            unsigned g[4];
#pragma unroll
            for (int u = 0; u < 4; u++) {
                const int s = col[jb + k + u];
                w[u] = wb[(k + u) * 4 + head];
                g[u] = hh[s * 64 + lane];
            }
#pragma unroll
            for (int u = 0; u < 4; u++) {
                const float2 g2 = unpk16(g[u]);
                den  += w[u];
                acc0 += w[u] * g2.x;
                acc1 += w[u] * g2.y;
            }
        }
        for (; k < cnt; k++) {
            const float w = wb[k * 4 + head];
            const float2 g2 = unpk16(hh[col[jb + k] * 64 + lane]);
            den  += w;
            acc0 += w * g2.x;
            acc1 += w * g2.y;
        }
        __asm__ volatile("" ::: "memory");
    }
    const float2 bb  = ((const float2*)b1)[lane];
    const float  inv = 1.f / (den + 1e-16f);
    float v0 = acc0 * inv + bb.x;
    float v1 = acc1 * inv + bb.y;
    v0 = v0 > 0.f ? v0 : (__expf(v0) - 1.f);
    v1 = v1 > 0.f ? v1 : (__expf(v1) - 1.f);
    acth[d * 64 + lane] = pk16(v0, v1);
}

// ---------------------------------------------------------------------------
// Fused layer-2 tail (verified R10/R11)
// ---------------------------------------------------------------------------
__global__ __launch_bounds__(256) void agg2_fused_kernel(
    const int* __restrict__ row_beg, const int* __restrict__ row_end,
    const int* __restrict__ col, const _Float16* __restrict__ h,
    const float* __restrict__ as2, const float* __restrict__ ad2,
    const float* __restrict__ b2, float* __restrict__ out)
{
    __shared__ float wbuf[4][64];   // 1 KB
    const int wv   = threadIdx.x >> 6;
    const int d    = __builtin_amdgcn_readfirstlane((blockIdx.x * 256 + threadIdx.x) >> 6);
    const int lane = threadIdx.x & 63;
    const int beg = row_beg[d], end = row_end[d];
    const float add = ad2[d];
    float* wb = wbuf[wv];

    float acc = 0.f, den = 0.f;

    for (int jb = beg; jb < end; jb += 64) {
        const int cnt = min(64, end - jb);
        {
            const int sl = col[jb + min(lane, cnt - 1)];
            wb[lane] = __expf(lrelu(as2[sl] + add));
        }
        __asm__ volatile("s_waitcnt lgkmcnt(0)" ::: "memory");

        int k = 0;
        for (; k + 16 <= cnt; k += 16) {
            float w[16], g[16];
#pragma unroll
            for (int u = 0; u < 16; u++) {
                const int s = col[jb + k + u];
                w[u] = wb[k + u];
                g[u] = (float)h[s * 64 + lane];
            }
#pragma unroll
            for (int u = 0; u < 16; u++) {
                den += w[u];
                acc += w[u] * g[u];
            }
        }
        for (; k + 4 <= cnt; k += 4) {
            float w[4], g[4];
#pragma unroll
            for (int u = 0; u < 4; u++) {
                const int s = col[jb + k + u];
                w[u] = wb[k + u];
                g[u] = (float)h[s * 64 + lane];
            }
#pragma unroll
            for (int u = 0; u < 4; u++) {
                den += w[u];
                acc += w[u] * g[u];
            }
        }
        for (; k < cnt; k++) {
            const float w = wb[k];
            den += w;
            acc += w * (float)h[col[jb + k] * 64 + lane];
        }
        __asm__ volatile("" ::: "memory");
    }
    out[d * 64 + lane] = acc / (den + 1e-16f) + b2[lane];
}

// ---------------------------------------------------------------------------
extern "C" void kernel_launch(void* const* d_in, const int* in_sizes, int n_in,
                              void* d_out, int out_size, void* d_ws, size_t ws_size,
                              hipStream_t stream)
{
    const float* x    = (const float*)d_in[0];
    const int*   ei   = (const int*)  d_in[1];
    const float* W1   = (const float*)d_in[2];
    const float* at_s1= (const float*)d_in[3];
    const float* at_d1= (const float*)d_in[4];
    const float* b1   = (const float*)d_in[5];
    const float* W2   = (const float*)d_in[6];
    const float* at_s2= (const float*)d_in[7];
    const float* at_d2= (const float*)d_in[8];
    const float* b2   = (const float*)d_in[9];
    float*       out  = (float*)d_out;

    const size_t NPAD = (size_t)NBUCK * MAXB;   // 1,605,632 padded slots

    // workspace layout (~48 MB)
    float* fw   = (float*)d_ws;
    float* as1  = fw;                  // NN*4
    float* ad1  = as1  + NN * 4;       // NN*4
    float* as2  = ad1  + NN * 4;       // NN
    float* ad2  = as2  + NN;           // NN
    _Float16* h1h   = (_Float16*)(ad2 + NN);   // NN*128
    _Float16* act1h = h1h  + (size_t)NN * 128; // NN*128
    _Float16* h2h   = act1h+ (size_t)NN * 128; // NN*64
    _Float16* w1t   = h2h  + (size_t)NN * 64;  // 16384
    _Float16* w2t   = w1t  + 16384;            // 8192
    int*   row_beg = (int*)(w2t + 8192);       // NN
    int*   row_end = row_beg + NN;             // NN
    int*   col     = row_end + NN;             // NPAD
    int*   bcnt    = col + NPAD;               // 256 (zeroed)
    unsigned* pairs = (unsigned*)(bcnt + 256); // NPAD

    hipMemsetAsync(bcnt, 0, 256 * sizeof(int), stream);

    const int node_wave_grid = NN / 4;      // 12500 blocks (wave per node)

    // dispatch 1: gemm1 (+alpha1) overlapped with bin (+W2 prep)
    gemm1_bin_kernel<<<GB + BINB, 256, 0, stream>>>(x, W1, W2, ei, at_s1, at_d1,
                        w1t, w2t, h1h, as1, ad1, bcnt, pairs);
    bsort_kernel    <<<NBUCK, 1024, 0, stream>>>(bcnt, pairs, row_beg, row_end, col);
    agg1_fused_kernel<<<node_wave_grid, 256, 0, stream>>>(row_beg, row_end, col,
                        (const unsigned*)h1h, as1, ad1, b1, (unsigned*)act1h);

    gemm2_mfma_kernel<<<GB, 256, 0, stream>>>(act1h, w2t, at_s2, at_d2, h2h, as2, ad2);
    agg2_fused_kernel<<<node_wave_grid, 256, 0, stream>>>(row_beg, row_end, col,
                        h2h, as2, ad2, b2, out);
}

// Round 13
// 212.067 us; speedup vs baseline: 1.4071x; 1.4071x over previous
//
#include <hip/hip_runtime.h>

#define NN    50000      // nodes
#define NE    800000     // edges (without self loops)
#define NET   850000     // NE + NN (with self loops)
#define NBUCK ((NN + 255) / 256)   // 196 dst-buckets of 256 nodes
#define MAXB  8192       // padded slots per bucket (avg 4352, sigma 66)

typedef __fp16 half2_t __attribute__((ext_vector_type(2)));
typedef _Float16 half8 __attribute__((ext_vector_type(8)));
typedef float floatx4 __attribute__((ext_vector_type(4)));

__device__ __forceinline__ float lrelu(float v) { return fmaxf(v, 0.2f * v); }
__device__ __forceinline__ unsigned pk16(float a, float b) {
    half2_t h = __builtin_amdgcn_cvt_pkrtz(a, b);
    return __builtin_bit_cast(unsigned, h);
}
__device__ __forceinline__ float2 unpk16(unsigned u) {
    half2_t h = __builtin_bit_cast(half2_t, u);
    return make_float2((float)h.x, (float)h.y);
}

// ---------------------------------------------------------------------------
// MFMA GEMM1 + alpha1 (verified R8-R11): fp32 x packed in-register.
// ---------------------------------------------------------------------------
__global__ __launch_bounds__(256) void gemm1_mfma_kernel(
    const float* __restrict__ x, const _Float16* __restrict__ w1t,
    const float* __restrict__ att_s, const float* __restrict__ att_d,
    _Float16* __restrict__ h1h, float* __restrict__ as, float* __restrict__ ad)
{
    __shared__ _Float16 hs[64 * 128];   // 16 KB
    const int t    = threadIdx.x;
    const int lane = t & 63;
    const int m    = lane & 15;
    const int q    = lane >> 4;
    const int wv   = t >> 6;
    const int gr0  = blockIdx.x * 64;
    const int rbase = gr0 + wv * 16;

    const int rme = rbase + m;
    const int rc  = rme < NN ? rme : NN - 1;
    const float* ap = x + (size_t)rc * 128 + q * 8;

    floatx4 acc[8];
#pragma unroll
    for (int nt = 0; nt < 8; nt++) acc[nt] = (floatx4){0.f, 0.f, 0.f, 0.f};

#pragma unroll
    for (int ks = 0; ks < 4; ks++) {
        const float4 f0 = *(const float4*)(ap + ks * 32);
        const float4 f1 = *(const float4*)(ap + ks * 32 + 4);
        const uint4 au = make_uint4(pk16(f0.x, f0.y), pk16(f0.z, f0.w),
                                    pk16(f1.x, f1.y), pk16(f1.z, f1.w));
        const half8 a = __builtin_bit_cast(half8, au);
#pragma unroll
        for (int nt = 0; nt < 8; nt++) {
            const half8 b = *(const half8*)(w1t + (nt * 16 + m) * 128 + ks * 32 + q * 8);
            acc[nt] = __builtin_amdgcn_mfma_f32_16x16x32_f16(a, b, acc[nt], 0, 0, 0);
        }
    }

    const int lrow0 = wv * 16 + q * 4;
#pragma unroll
    for (int nt = 0; nt < 8; nt++)
#pragma unroll
        for (int r = 0; r < 4; r++)
            hs[(lrow0 + r) * 128 + nt * 16 + m] = (_Float16)acc[nt][r];
    __syncthreads();

#pragma unroll
    for (int i = t; i < 1024; i += 256) {
        const int row = i >> 4;
        if (gr0 + row < NN)
            ((half8*)h1h)[(size_t)(gr0 + row) * 16 + (i & 15)] = ((const half8*)hs)[i];
    }

    const int arow = t >> 2, hd = t & 3;
    const int grow = gr0 + arow;
    float ps = 0.f, pd = 0.f;
    const half8*  hp8 = (const half8*)(hs + arow * 128 + hd * 32);
    const float4* s4  = (const float4*)(att_s + hd * 32);
    const float4* d4  = (const float4*)(att_d + hd * 32);
#pragma unroll
    for (int cc = 0; cc < 4; cc++) {
        const half8 hv = hp8[cc];
        const float4 a = s4[cc * 2], b = s4[cc * 2 + 1];
        const float4 c = d4[cc * 2], e = d4[cc * 2 + 1];
        ps += (float)hv[0]*a.x + (float)hv[1]*a.y + (float)hv[2]*a.z + (float)hv[3]*a.w
            + (float)hv[4]*b.x + (float)hv[5]*b.y + (float)hv[6]*b.z + (float)hv[7]*b.w;
        pd += (float)hv[0]*c.x + (float)hv[1]*c.y + (float)hv[2]*c.z + (float)hv[3]*c.w
            + (float)hv[4]*e.x + (float)hv[5]*e.y + (float)hv[6]*e.z + (float)hv[7]*e.w;
    }
    if (grow < NN) {
        as[grow * 4 + hd] = ps;
        ad[grow * 4 + hd] = pd;
    }
}

// ---------------------------------------------------------------------------
// MFMA GEMM2 + alpha2 (verified R8-R11)
// ---------------------------------------------------------------------------
__global__ __launch_bounds__(256) void gemm2_mfma_kernel(
    const _Float16* __restrict__ ah, const _Float16* __restrict__ w2t,
    const float* __restrict__ att_s, const float* __restrict__ att_d,
    _Float16* __restrict__ h2h, float* __restrict__ as, float* __restrict__ ad)
{
    __shared__ _Float16 hs[64 * 64];    // 8 KB
    const int t    = threadIdx.x;
    const int lane = t & 63;
    const int m    = lane & 15;
    const int q    = lane >> 4;
    const int wv   = t >> 6;
    const int gr0  = blockIdx.x * 64;
    const int rbase = gr0 + wv * 16;

    const int rme = rbase + m;
    const int rc  = rme < NN ? rme : NN - 1;
    const _Float16* ap = ah + (size_t)rc * 128 + q * 8;

    floatx4 acc[4];
#pragma unroll
    for (int nt = 0; nt < 4; nt++) acc[nt] = (floatx4){0.f, 0.f, 0.f, 0.f};

#pragma unroll
    for (int ks = 0; ks < 4; ks++) {
        const half8 a = *(const half8*)(ap + ks * 32);
#pragma unroll
        for (int nt = 0; nt < 4; nt++) {
            const half8 b = *(const half8*)(w2t + (nt * 16 + m) * 128 + ks * 32 + q * 8);
            acc[nt] = __builtin_amdgcn_mfma_f32_16x16x32_f16(a, b, acc[nt], 0, 0, 0);
        }
    }

    const int lrow0 = wv * 16 + q * 4;
#pragma unroll
    for (int nt = 0; nt < 4; nt++)
#pragma unroll
        for (int r = 0; r < 4; r++)
            hs[(lrow0 + r) * 64 + nt * 16 + m] = (_Float16)acc[nt][r];
    __syncthreads();

#pragma unroll
    for (int i = t; i < 512; i += 256) {
        const int row = i >> 3;
        if (gr0 + row < NN)
            ((half8*)h2h)[(size_t)(gr0 + row) * 8 + (i & 7)] = ((const half8*)hs)[i];
    }

    const int arow = t >> 2, sg = t & 3;
    const int grow = gr0 + arow;
    float ps = 0.f, pd = 0.f;
    const half8*  hp8 = (const half8*)(hs + arow * 64 + sg * 16);
    const float4* s4  = (const float4*)(att_s + sg * 16);
    const float4* d4  = (const float4*)(att_d + sg * 16);
#pragma unroll
    for (int cc = 0; cc < 2; cc++) {
        const half8 hv = hp8[cc];
        const float4 a = s4[cc * 2], b = s4[cc * 2 + 1];
        const float4 c = d4[cc * 2], e = d4[cc * 2 + 1];
        ps += (float)hv[0]*a.x + (float)hv[1]*a.y + (float)hv[2]*a.z + (float)hv[3]*a.w
            + (float)hv[4]*b.x + (float)hv[5]*b.y + (float)hv[6]*b.z + (float)hv[7]*b.w;
        pd += (float)hv[0]*c.x + (float)hv[1]*c.y + (float)hv[2]*c.z + (float)hv[3]*c.w
            + (float)hv[4]*e.x + (float)hv[5]*e.y + (float)hv[6]*e.z + (float)hv[7]*e.w;
    }
    ps += __shfl_down(ps, 2);  pd += __shfl_down(pd, 2);
    ps += __shfl_down(ps, 1);  pd += __shfl_down(pd, 1);
    if (sg == 0 && grow < NN) { as[grow] = ps; ad[grow] = pd; }
}

// ---------------------------------------------------------------------------
// bin (+ folded W prep in blocks 0..23): pairs packed to uint32
// (src in bits 0..15 — NN<65536 — and dst-local in bits 16..23).
// ---------------------------------------------------------------------------
__global__ __launch_bounds__(1024) void bin_kernel(const int* __restrict__ ei,
                                                   const float* __restrict__ W1,
                                                   const float* __restrict__ W2,
                                                   _Float16* __restrict__ w1t,
                                                   _Float16* __restrict__ w2t,
                                                   int* __restrict__ bcnt,
                                                   unsigned* __restrict__ pairs)
{
    // folded weight prep: 24 blocks x 1024 = 24576 elements exact
    if (blockIdx.x < 24) {
        const int idx = blockIdx.x * 1024 + threadIdx.x;
        if (idx < 16384) {
            const int k = idx >> 7, n = idx & 127;
            w1t[n * 128 + k] = (_Float16)W1[idx];
        } else {
            const int j = idx - 16384;
            const int k = j >> 6, n = j & 63;
            w2t[n * 128 + k] = (_Float16)W2[j];
        }
    }

    __shared__ int hist[NBUCK], base[NBUCK], cur[NBUCK];
    const int t = threadIdx.x;
    if (t < NBUCK) { hist[t] = 0; cur[t] = 0; }
    __syncthreads();
    const int e = blockIdx.x * 1024 + t;
    int s = 0, d = 0, bk = 0;
    const bool ok = e < NET;
    if (ok) {
        if (e < NE) { s = ei[e]; d = ei[NE + e]; } else { s = d = e - NE; }
        bk = d >> 8;
        atomicAdd(&hist[bk], 1);
    }
    __syncthreads();
    if (t < NBUCK && hist[t]) base[t] = atomicAdd(&bcnt[t], hist[t]);
    __syncthreads();
    if (ok) {
        const int r = atomicAdd(&cur[bk], 1);
        pairs[(size_t)bk * MAXB + base[bk] + r] =
            (unsigned)s | ((unsigned)(d & 255) << 16);
    }
}

// ---------------------------------------------------------------------------
// bsort (1024 threads): per-bucket LDS counting sort, emits row_beg/row_end
// and src-only col. Packed pairs: src = p & 0xFFFF, dlocal = p >> 16.
// ---------------------------------------------------------------------------
__global__ __launch_bounds__(1024) void bsort_kernel(
    const int* __restrict__ bcnt, const unsigned* __restrict__ pairs,
    int* __restrict__ row_beg, int* __restrict__ row_end,
    int* __restrict__ col)
{
    __shared__ int hist[256], cur[256], sh[256];
    __shared__ int outl[MAXB];
    const int b = blockIdx.x, t = threadIdx.x;
    const int m = bcnt[b];
    const int gbase = b * MAXB;
    if (t < 256) hist[t] = 0;
    __syncthreads();
    for (int i = t; i < m; i += 1024)
        atomicAdd(&hist[pairs[gbase + i] >> 16], 1);
    __syncthreads();
    if (t < 256) sh[t] = hist[t];
    __syncthreads();
#pragma unroll
    for (int off = 1; off < 256; off <<= 1) {
        int u = (t < 256 && t >= off) ? sh[t - off] : 0;
        __syncthreads();
        if (t < 256) sh[t] += u;
        __syncthreads();
    }
    if (t < 256) {
        const int ex = sh[t] - hist[t];
        cur[t] = ex;
        const int node = (b << 8) + t;
        if (node < NN) {
            row_beg[node] = gbase + ex;
            row_end[node] = gbase + ex + hist[t];
        }
    }
    __syncthreads();
    for (int i = t; i < m; i += 1024) {
        const unsigned p = pairs[gbase + i];
        const int r = atomicAdd(&cur[p >> 16], 1);
        outl[r] = (int)(p & 0xFFFFu);
    }
    __syncthreads();
    for (int i = t; i < m; i += 1024) col[gbase + i] = outl[i];
}

// ---------------------------------------------------------------------------
// Fused layer-1 tail (verified R10/R11): LDS-staged lane-parallel weights.
// ---------------------------------------------------------------------------
__global__ __launch_bounds__(256) void agg1_fused_kernel(
    const int* __restrict__ row_beg, const int* __restrict__ row_end,
    const int* __restrict__ col, const unsigned* __restrict__ hh,
    const float* __restrict__ as1, const float* __restrict__ ad1,
    const float* __restrict__ b1, unsigned* __restrict__ acth)
{
    __shared__ float wbuf[4][64 * 4];   // [wave][edge*4+head], 4 KB
    const int wv   = threadIdx.x >> 6;
    const int d    = __builtin_amdgcn_readfirstlane((blockIdx.x * 256 + threadIdx.x) >> 6);
    const int lane = threadIdx.x & 63;
    const int head = lane >> 4;
    const int beg = row_beg[d], end = row_end[d];       // s_loads (d uniform)
    const float4 ad4 = ((const float4*)ad1)[d];
    float* wb = wbuf[wv];

    float acc0 = 0.f, acc1 = 0.f, den = 0.f;

    for (int jb = beg; jb < end; jb += 64) {
        const int cnt = min(64, end - jb);
        {
            const int sl = col[jb + min(lane, cnt - 1)];
            const float4 a = ((const float4*)as1)[sl];
            float4 w4;
            w4.x = __expf(lrelu(a.x + ad4.x));
            w4.y = __expf(lrelu(a.y + ad4.y));
            w4.z = __expf(lrelu(a.z + ad4.z));
            w4.w = __expf(lrelu(a.w + ad4.w));
            ((float4*)wb)[lane] = w4;
        }
        __asm__ volatile("s_waitcnt lgkmcnt(0)" ::: "memory");

        int k = 0;
        for (; k + 16 <= cnt; k += 16) {
            float    w[16];
            unsigned g[16];
#pragma unroll
            for (int u = 0; u < 16; u++) {
                const int s = col[jb + k + u];        // s_load (uniform)
                w[u] = wb[(k + u) * 4 + head];        // ds_read broadcast
                g[u] = hh[s * 64 + lane];             // saddr + voffset
            }
#pragma unroll
            for (int u = 0; u < 16; u++) {
                const float2 g2 = unpk16(g[u]);
                den  += w[u];
                acc0 += w[u] * g2.x;
                acc1 += w[u] * g2.y;
            }
        }
        for (; k + 4 <= cnt; k += 4) {
            float    w[4];
            unsigned g[4];
#pragma unroll
            for (int u = 0; u < 4; u++) {
                const int s = col[jb + k + u];
                w[u] = wb[(k + u) * 4 + head];
                g[u] = hh[s * 64 + lane];
            }
#pragma unroll
            for (int u = 0; u < 4; u++) {
                const float2 g2 = unpk16(g[u]);
                den  += w[u];
                acc0 += w[u] * g2.x;
                acc1 += w[u] * g2.y;
            }
        }
        for (; k < cnt; k++) {
            const float w = wb[k * 4 + head];
            const float2 g2 = unpk16(hh[col[jb + k] * 64 + lane]);
            den  += w;
            acc0 += w * g2.x;
            acc1 += w * g2.y;
        }
        __asm__ volatile("" ::: "memory");
    }
    const float2 bb  = ((const float2*)b1)[lane];
    const float  inv = 1.f / (den + 1e-16f);
    float v0 = acc0 * inv + bb.x;
    float v1 = acc1 * inv + bb.y;
    v0 = v0 > 0.f ? v0 : (__expf(v0) - 1.f);
    v1 = v1 > 0.f ? v1 : (__expf(v1) - 1.f);
    acth[d * 64 + lane] = pk16(v0, v1);
}

// ---------------------------------------------------------------------------
// Fused layer-2 tail (verified R10/R11)
// ---------------------------------------------------------------------------
__global__ __launch_bounds__(256) void agg2_fused_kernel(
    const int* __restrict__ row_beg, const int* __restrict__ row_end,
    const int* __restrict__ col, const _Float16* __restrict__ h,
    const float* __restrict__ as2, const float* __restrict__ ad2,
    const float* __restrict__ b2, float* __restrict__ out)
{
    __shared__ float wbuf[4][64];   // 1 KB
    const int wv   = threadIdx.x >> 6;
    const int d    = __builtin_amdgcn_readfirstlane((blockIdx.x * 256 + threadIdx.x) >> 6);
    const int lane = threadIdx.x & 63;
    const int beg = row_beg[d], end = row_end[d];
    const float add = ad2[d];
    float* wb = wbuf[wv];

    float acc = 0.f, den = 0.f;

    for (int jb = beg; jb < end; jb += 64) {
        const int cnt = min(64, end - jb);
        {
            const int sl = col[jb + min(lane, cnt - 1)];
            wb[lane] = __expf(lrelu(as2[sl] + add));
        }
        __asm__ volatile("s_waitcnt lgkmcnt(0)" ::: "memory");

        int k = 0;
        for (; k + 16 <= cnt; k += 16) {
            float w[16], g[16];
#pragma unroll
            for (int u = 0; u < 16; u++) {
                const int s = col[jb + k + u];
                w[u] = wb[k + u];
                g[u] = (float)h[s * 64 + lane];
            }
#pragma unroll
            for (int u = 0; u < 16; u++) {
                den += w[u];
                acc += w[u] * g[u];
            }
        }
        for (; k + 4 <= cnt; k += 4) {
            float w[4], g[4];
#pragma unroll
            for (int u = 0; u < 4; u++) {
                const int s = col[jb + k + u];
                w[u] = wb[k + u];
                g[u] = (float)h[s * 64 + lane];
            }
#pragma unroll
            for (int u = 0; u < 4; u++) {
                den += w[u];
                acc += w[u] * g[u];
            }
        }
        for (; k < cnt; k++) {
            const float w = wb[k];
            den += w;
            acc += w * (float)h[col[jb + k] * 64 + lane];
        }
        __asm__ volatile("" ::: "memory");
    }
    out[d * 64 + lane] = acc / (den + 1e-16f) + b2[lane];
}

// ---------------------------------------------------------------------------
extern "C" void kernel_launch(void* const* d_in, const int* in_sizes, int n_in,
                              void* d_out, int out_size, void* d_ws, size_t ws_size,
                              hipStream_t stream)
{
    const float* x    = (const float*)d_in[0];
    const int*   ei   = (const int*)  d_in[1];
    const float* W1   = (const float*)d_in[2];
    const float* at_s1= (const float*)d_in[3];
    const float* at_d1= (const float*)d_in[4];
    const float* b1   = (const float*)d_in[5];
    const float* W2   = (const float*)d_in[6];
    const float* at_s2= (const float*)d_in[7];
    const float* at_d2= (const float*)d_in[8];
    const float* b2   = (const float*)d_in[9];
    float*       out  = (float*)d_out;

    const size_t NPAD = (size_t)NBUCK * MAXB;   // 1,605,632 padded slots

    // workspace layout (~48 MB)
    float* fw   = (float*)d_ws;
    float* as1  = fw;                  // NN*4
    float* ad1  = as1  + NN * 4;       // NN*4
    float* as2  = ad1  + NN * 4;       // NN
    float* ad2  = as2  + NN;           // NN
    _Float16* h1h   = (_Float16*)(ad2 + NN);   // NN*128
    _Float16* act1h = h1h  + (size_t)NN * 128; // NN*128
    _Float16* h2h   = act1h+ (size_t)NN * 128; // NN*64
    _Float16* w1t   = h2h  + (size_t)NN * 64;  // 16384
    _Float16* w2t   = w1t  + 16384;            // 8192
    int*   row_beg = (int*)(w2t + 8192);       // NN
    int*   row_end = row_beg + NN;             // NN
    int*   col     = row_end + NN;             // NPAD
    int*   bcnt    = col + NPAD;               // 256 (zeroed)
    unsigned* pairs = (unsigned*)(bcnt + 256); // NPAD

    hipMemsetAsync(bcnt, 0, 256 * sizeof(int), stream);

    const int eg1024 = (NET + 1023) / 1024;
    const int gemm_grid = (NN + 63) / 64;   // 782
    const int node_wave_grid = NN / 4;      // 12500 blocks (wave per node)

    bin_kernel  <<<eg1024, 1024, 0, stream>>>(ei, W1, W2, w1t, w2t, bcnt, pairs);
    bsort_kernel<<<NBUCK, 1024, 0, stream>>>(bcnt, pairs, row_beg, row_end, col);

    // layer 1
    gemm1_mfma_kernel<<<gemm_grid, 256, 0, stream>>>(x, w1t, at_s1, at_d1, h1h, as1, ad1);
    agg1_fused_kernel<<<node_wave_grid, 256, 0, stream>>>(row_beg, row_end, col,
                        (const unsigned*)h1h, as1, ad1, b1, (unsigned*)act1h);

    // layer 2
    gemm2_mfma_kernel<<<gemm_grid, 256, 0, stream>>>(act1h, w2t, at_s2, at_d2, h2h, as2, ad2);
    agg2_fused_kernel<<<node_wave_grid, 256, 0, stream>>>(row_beg, row_end, col,
                        h2h, as2, ad2, b2, out);
}